// Round 6
// baseline (239.696 us; speedup 1.0000x reference)
//
#include <hip/hip_runtime.h>

#define NN   2048
#define ROWS 4096          // B*N
#define RPB  32            // rows per block (halved grid vs r4)
#define CSPLIT 4           // column splits; block covers 256 float4 cols
#define NBY  (ROWS/RPB)    // 128
#define PSTR 257           // LDS partial stride
#define NBLK (CSPLIT*NBY)  // 512 blocks = 2/CU needed; capacity >=4/CU -> 2x slack

#define SUBW 32            // arrivals per sub-counter
#define NSUB (NBLK/SUBW)   // 16 sub-counters
#define CPAD 16            // ints per counter (64B padding)
#define BARSTRIDE ((NSUB+1)*CPAD)   // ints per barrier instance
#define SPIN_LIMIT (1<<21)          // ~100ms escape: wrong-answer beats dead-container

__device__ __forceinline__ float fsig(float x) {
    float e = __expf(-x);
    return __builtin_amdgcn_rcpf(1.0f + e);
}

// Agent-scope relaxed atomics: cross-XCD-coherent data path (execute at the
// coherence point; per-XCD L1/L2 never hold stale/dirty copies).  No fences,
// no L2 writeback/invalidate anywhere (round-3 lesson).
__device__ __forceinline__ float gload(const float* p) {
    return __hip_atomic_load(p, __ATOMIC_RELAXED, __HIP_MEMORY_SCOPE_AGENT);
}
__device__ __forceinline__ void gstore(float* p, float v) {
    __hip_atomic_store(p, v, __ATOMIC_RELAXED, __HIP_MEMORY_SCOPE_AGENT);
}
__device__ __forceinline__ void gatomic_add(float* p, float v) {
    __hip_atomic_fetch_add(p, v, __ATOMIC_RELAXED, __HIP_MEMORY_SCOPE_AGENT);
}

// Fully-relaxed two-level grid barrier (round-4-proven at 87us/kernel).
// __syncthreads drains vmcnt(0) so all sc1 stores/atomics reached the
// coherence point before the arrive; readers use sc1 loads -> relaxed is
// sufficient end-to-end.  SPIN_LIMIT makes a residency failure produce a
// wrong answer (absmax-detectable) instead of a hung container (round-5 bug).
__device__ __forceinline__ void gridbar(int* cnt, int bid) {
    __syncthreads();                      // s_waitcnt vmcnt(0) + s_barrier
    if (threadIdx.x == 0) {
        asm volatile("" ::: "memory");
        int* sub  = cnt + (bid & (NSUB - 1)) * CPAD;
        int* root = cnt + NSUB * CPAD;
        int old = __hip_atomic_fetch_add(sub, 1, __ATOMIC_RELAXED,
                                         __HIP_MEMORY_SCOPE_AGENT);
        if (old == SUBW - 1)
            __hip_atomic_fetch_add(root, 1, __ATOMIC_RELAXED,
                                   __HIP_MEMORY_SCOPE_AGENT);
        int tries = 0;
        while (__hip_atomic_load(root, __ATOMIC_RELAXED,
                                 __HIP_MEMORY_SCOPE_AGENT) < NSUB) {
            __builtin_amdgcn_s_sleep(2);
            if (++tries > SPIN_LIMIT) break;
        }
        asm volatile("" ::: "memory");
    }
    __syncthreads();
}

// ---------------------------------------------------------------------------
// One pass over this block's 32 rows x 256 f4-cols.  Single per-pass r/c
// accumulators (relaxed atomicAdd, host-pre-zeroed): prologue reads 2 floats
// per index.  d0/d1[32]: register-resident F1-F0, filled at T==0; T==4
// re-reads F (L3-resident) to write outF.  Main loop runs as two 16-row
// halves sharing the part[] LDS buffer.
// ---------------------------------------------------------------------------
template<int T>
__device__ __forceinline__ void do_pass(
    float* __restrict__ stCur, const float* __restrict__ stPrev,
    const float* __restrict__ stPP,
    float* __restrict__ sdif, float* __restrict__ cdif,
    float* __restrict__ part,
    float (&d0)[RPB], float (&d1)[RPB],
    const float4* __restrict__ F,
    const float2* __restrict__ S2, const float2* __restrict__ C2,
    const float* __restrict__ rprev, const float* __restrict__ cprev,
    float* __restrict__ rout, float* __restrict__ cout,
    float* __restrict__ aSout, float4* __restrict__ outF,
    int tid, int sx, int by, int bloc, int row0, int base,
    float w0, float w1)
{
    // ---- prologue: state for the 544 indices this block touches ----
    for (int idx = tid; idx < 512 + RPB; idx += 256) {
        int il = (idx < 512) ? (sx * 512 + idx) : (bloc * RPB + idx - 512);
        int g  = base + il;
        float cur;
        if (T == 0) {
            float2 sv = S2[g], cv = C2[g];
            float sd = sv.y - sv.x;
            sdif[idx] = sd;
            cdif[idx] = cv.x - cv.y;
            cur = fsig(sd);                       // aS_0
        } else {
            float rs = gload(rprev + g);          // summed r_{T-1}
            float cs = gload(cprev + g);          // summed c_{T-1}
            float qc = (T == 1) ? fsig(cdif[idx])                      // qC0_0
                                : fsig(cdif[idx] - w0 * stPP[idx]);    // qC0_{T-1}
            cur = fsig(sdif[idx] + w1*cs - w0*qc - w1*rs);             // aS_T
        }
        stCur[idx] = cur;
        if (T >= 3 && sx == 0 && idx >= 512) gstore(aSout + g, cur);   // aS_3/aS_4
    }
    __syncthreads();

    const int j = sx * 256 + tid;                  // float4 column
    const float wq0 = 1.0f - stCur[2*tid];
    const float wq1 = 1.0f - stCur[2*tid + 1];
    const float bp0 = (T == 0) ? 0.0f : 1.0f - stPrev[2*tid];
    const float bp1 = (T == 0) ? 0.0f : 1.0f - stPrev[2*tid + 1];

    float c0 = 0.0f, c1 = 0.0f;

#pragma unroll
    for (int h = 0; h < 2; h++) {                 // two 16-row halves
#pragma unroll
        for (int i = 0; i < 16; i++) {            // static: h,i compile-time
            const int ir  = h * 16 + i;           // d[] index stays register
            const float a_c = stCur[512 + ir];
            float s0, s1;
            if (T == 0) {
                const float4 f = F[(size_t)(row0 + ir) * (NN/2) + j];
                d0[ir] = f.y - f.x;
                d1[ir] = f.w - f.z;
                s0 = fsig(d0[ir]);
                s1 = fsig(d1[ir]);
            } else {
                const float m1 = w1 * stPrev[512 + ir];
                s0 = fsig(d0[ir] - m1 * bp0);
                s1 = fsig(d1[ir] - m1 * bp1);
            }
            c0 += s0 * a_c;
            c1 += s1 * a_c;
            part[i * PSTR + tid] = s0 * wq0 + s1 * wq1;
            if (T == 4) {                          // L3-resident F re-read
                const float4 f = F[(size_t)(row0 + ir) * (NN/2) + j];
                const float mw = w1 * a_c;
                float4 o;
                o.x = f.x + mw * wq0; o.y = f.y;
                o.z = f.z + mw * wq1; o.w = f.w;
                outF[(size_t)(row0 + ir) * (NN/2) + j] = o;
            }
        }
        __syncthreads();
        // r-reduce for this half's 16 rows, one relaxed atomic per row
        {
            const int row = tid >> 4, seg = tid & 15;
            float s = 0.0f;
#pragma unroll
            for (int u = 0; u < 16; u++) s += part[row * PSTR + seg * 16 + u];
#pragma unroll
            for (int off = 8; off > 0; off >>= 1) s += __shfl_down(s, off, 16);
            if (seg == 0) gatomic_add(rout + row0 + h * 16 + row, s);
        }
        __syncthreads();                           // part[] reused by next half
    }

    // c: relaxed agent atomics into the single per-pass accumulator
    gatomic_add(cout + base + 2*j,     c0);
    gatomic_add(cout + base + 2*j + 1, c1);
}

// Fused persistent kernel: all 5 passes, relaxed two-level grid barrier.
// REGULAR launch: 512 blocks, LDS 27.3KB (5/CU), VGPR<=128 (4/CU) -> need
// only 2/CU: 2x residency slack (round-5 deadlock fix).
__global__ __launch_bounds__(256, 4) void kfused(
    const float4* __restrict__ F,
    const float2* __restrict__ S2, const float2* __restrict__ C2,
    const float* __restrict__ w,
    float* __restrict__ ws,
    float4* __restrict__ outF)
{
    __shared__ float st[3][512 + RPB]; // rotating aS state
    __shared__ float sdif[512 + RPB];  // S1-S0 (constant across passes)
    __shared__ float cdif[512 + RPB];  // C0-C1 (constant across passes)
    __shared__ float part[16 * PSTR];

    const int tid  = threadIdx.x;
    const int sx   = blockIdx.x;          // 0..3   column split
    const int by   = blockIdx.y;          // 0..127 row group
    const int row0 = by * RPB;
    const int b    = by >> 6;             // batch (64 row-groups per batch)
    const int bloc = by & 63;             // row group within batch
    const int base = b * NN;
    const int bid  = by * CSPLIT + sx;    // linear block id
    const float w0 = w[0], w1 = w[1];

    float d0[RPB], d1[RPB];               // register-resident F1-F0 (64 VGPR)

    // ws layout (floats): r[5][ROWS] | c[5][ROWS] | aS[4][ROWS] | bar
    float* rb = ws;                      // 5 * ROWS
    float* cb = ws + 5 * ROWS;           // 5 * ROWS
    float* ab = ws + 10 * ROWS;          // 4 * ROWS (aS_1..aS_4)
    int*   bar = (int*)(ws + 14 * ROWS);
#define RB(t) (rb + (t) * ROWS)
#define CB(t) (cb + (t) * ROWS)
#define AB(t) (ab + ((t) - 1) * ROWS)

    do_pass<0>(st[0], st[2], st[1], sdif, cdif, part, d0, d1, F, S2, C2,
               nullptr, nullptr, RB(0), CB(0), nullptr, nullptr,
               tid, sx, by, bloc, row0, base, w0, w1);
    gridbar(bar + 0*BARSTRIDE, bid);
    do_pass<1>(st[1], st[0], st[2], sdif, cdif, part, d0, d1, F, S2, C2,
               RB(0), CB(0), RB(1), CB(1), nullptr, nullptr,
               tid, sx, by, bloc, row0, base, w0, w1);
    gridbar(bar + 1*BARSTRIDE, bid);
    do_pass<2>(st[2], st[1], st[0], sdif, cdif, part, d0, d1, F, S2, C2,
               RB(1), CB(1), RB(2), CB(2), nullptr, nullptr,
               tid, sx, by, bloc, row0, base, w0, w1);
    gridbar(bar + 2*BARSTRIDE, bid);
    do_pass<3>(st[0], st[2], st[1], sdif, cdif, part, d0, d1, F, S2, C2,
               RB(2), CB(2), RB(3), CB(3), AB(3), nullptr,
               tid, sx, by, bloc, row0, base, w0, w1);
    gridbar(bar + 3*BARSTRIDE, bid);
    do_pass<4>(st[1], st[0], st[2], sdif, cdif, part, d0, d1, F, S2, C2,
               RB(3), CB(3), RB(4), CB(4), AB(4), outF,
               tid, sx, by, bloc, row0, base, w0, w1);
}

// Epilogue: out_S, out_C from completed r_4, c_4, aS_4, aS_3.
__global__ void kfin(const float2* __restrict__ S2, const float2* __restrict__ C2,
                     const float* __restrict__ w,
                     const float* __restrict__ rpart, const float* __restrict__ cpart,
                     const float* __restrict__ aS4, const float* __restrict__ aS3,
                     float2* __restrict__ outS, float2* __restrict__ outC)
{
    int idx = blockIdx.x * blockDim.x + threadIdx.x;
    if (idx >= ROWS) return;
    float w0 = w[0], w1 = w[1];
    float rs = rpart[idx];
    float cs = cpart[idx];
    float2 sv = S2[idx], cv = C2[idx];
    float qc4 = fsig(cv.x - cv.y - w0 * aS3[idx]);
    float2 os, oc;
    os.x = sv.x + w0 * qc4 + w1 * rs;
    os.y = sv.y + w1 * cs;
    oc.x = cv.x;
    oc.y = cv.y + w0 * aS4[idx];
    outS[idx] = os;
    outC[idx] = oc;
}

extern "C" void kernel_launch(void* const* d_in, const int* in_sizes, int n_in,
                              void* d_out, int out_size, void* d_ws, size_t ws_size,
                              hipStream_t stream)
{
    const float2* S2 = (const float2*)d_in[0];
    const float2* C2 = (const float2*)d_in[1];
    const float4* F4 = (const float4*)d_in[2];
    const float*  w  = (const float*)d_in[3];
    float* out = (float*)d_out;
    float* ws  = (float*)d_ws;

    float* rb = ws;
    float* cb = ws + 5 * ROWS;
    float* ab = ws + 10 * ROWS;
    int*   bar = (int*)(ws + 14 * ROWS);

    float* outS = out;
    float* outC = out + 2 * ROWS;
    float4* outF = (float4*)(out + 4 * ROWS);

    // zero r+c accumulators (160 KB) + barrier counters; in-graph so they
    // reset on every replay
    hipMemsetAsync(ws, 0, 10 * (size_t)ROWS * sizeof(float), stream);
    hipMemsetAsync(bar, 0, 4 * BARSTRIDE * sizeof(int), stream);

    dim3 gb(CSPLIT, NBY), bb(256, 1, 1);
    kfused<<<gb, bb, 0, stream>>>(F4, S2, C2, w, ws, outF);
    kfin<<<dim3(ROWS/256), bb, 0, stream>>>(S2, C2, w,
                                            rb + 4 * ROWS, cb + 4 * ROWS,
                                            ab + 3 * ROWS, ab + 2 * ROWS,
                                            (float2*)outS, (float2*)outC);
}

// Round 7
// 208.011 us; speedup vs baseline: 1.1523x; 1.1523x over previous
//
#include <hip/hip_runtime.h>

#define NN   2048
#define ROWS 4096          // B*N
#define RPB  16            // rows per block (r4-proven: d[16] fits registers)
#define CSPLIT 4           // column splits; block covers 256 float4 cols
#define NBY  (ROWS/RPB)    // 256
#define PSTR 257           // LDS partial stride
#define NBLK (CSPLIT*NBY)  // 1024 blocks = 4/CU

#define SUBW 32            // arrivals per sub-counter
#define NSUB (NBLK/SUBW)   // 32 sub-counters
#define CPAD 16            // ints per counter (64B padding)
#define BARSTRIDE ((NSUB+1)*CPAD)   // ints per barrier instance
#define NBAR 5             // 4 inter-pass + 1 pre-epilogue
#define SPIN_LIMIT (1<<21) // ~100ms escape: wrong-answer beats dead-container

__device__ __forceinline__ float fsig(float x) {
    float e = __expf(-x);
    return __builtin_amdgcn_rcpf(1.0f + e);
}

// Agent-scope relaxed atomics: cross-XCD-coherent data path (execute at the
// coherence point; per-XCD L1/L2 never hold stale/dirty copies).  No fences,
// no L2 writeback/invalidate anywhere (round-3 lesson).
__device__ __forceinline__ float gload(const float* p) {
    return __hip_atomic_load(p, __ATOMIC_RELAXED, __HIP_MEMORY_SCOPE_AGENT);
}
__device__ __forceinline__ void gatomic_add(float* p, float v) {
    __hip_atomic_fetch_add(p, v, __ATOMIC_RELAXED, __HIP_MEMORY_SCOPE_AGENT);
}

// Fully-relaxed two-level grid barrier (r4-proven).  __syncthreads drains
// vmcnt(0) so all sc1 stores/atomics reached the coherence point before the
// arrive; readers use sc1 loads -> relaxed suffices end-to-end.
__device__ __forceinline__ void gridbar(int* cnt, int bid) {
    __syncthreads();                      // s_waitcnt vmcnt(0) + s_barrier
    if (threadIdx.x == 0) {
        asm volatile("" ::: "memory");
        int* sub  = cnt + (bid & (NSUB - 1)) * CPAD;
        int* root = cnt + NSUB * CPAD;
        int old = __hip_atomic_fetch_add(sub, 1, __ATOMIC_RELAXED,
                                         __HIP_MEMORY_SCOPE_AGENT);
        if (old == SUBW - 1)
            __hip_atomic_fetch_add(root, 1, __ATOMIC_RELAXED,
                                   __HIP_MEMORY_SCOPE_AGENT);
        int tries = 0;
        while (__hip_atomic_load(root, __ATOMIC_RELAXED,
                                 __HIP_MEMORY_SCOPE_AGENT) < NSUB) {
            __builtin_amdgcn_s_sleep(1);
            if (++tries > SPIN_LIMIT) break;
        }
        asm volatile("" ::: "memory");
    }
    __syncthreads();
}

// ---------------------------------------------------------------------------
// One pass over 16 rows x 256 f4-cols.  Single per-pass r/c accumulators
// (relaxed fabric atomicAdd, host-pre-zeroed): prologue reads 2 floats/idx.
// d0/d1[16]: register-resident F1-F0 (filled at T==0; 32 VGPR, no spill).
// T==4 re-reads F (L3-resident) to write outF.  No aS workspace: epilogue
// reads aS_3/aS_4 straight from the LDS rotation.
// ---------------------------------------------------------------------------
template<int T>
__device__ __forceinline__ void do_pass(
    float* __restrict__ stCur, const float* __restrict__ stPrev,
    const float* __restrict__ stPP,
    float* __restrict__ sdif, float* __restrict__ cdif,
    float* __restrict__ part,
    float (&d0)[RPB], float (&d1)[RPB],
    const float4* __restrict__ F,
    const float2* __restrict__ S2, const float2* __restrict__ C2,
    const float* __restrict__ rprev, const float* __restrict__ cprev,
    float* __restrict__ rout, float* __restrict__ cout,
    float4* __restrict__ outF,
    int tid, int sx, int by, int bloc, int row0, int base,
    float w0, float w1)
{
    // ---- prologue: state for the 528 indices this block touches ----
    for (int idx = tid; idx < 512 + RPB; idx += 256) {
        int il = (idx < 512) ? (sx * 512 + idx) : (bloc * RPB + idx - 512);
        int g  = base + il;
        float cur;
        if (T == 0) {
            float2 sv = S2[g], cv = C2[g];
            float sd = sv.y - sv.x;
            sdif[idx] = sd;
            cdif[idx] = cv.x - cv.y;
            cur = fsig(sd);                       // aS_0
        } else {
            float rs = gload(rprev + g);          // summed r_{T-1}
            float cs = gload(cprev + g);          // summed c_{T-1}
            float qc = (T == 1) ? fsig(cdif[idx])                      // qC0_0
                                : fsig(cdif[idx] - w0 * stPP[idx]);    // qC0_{T-1}
            cur = fsig(sdif[idx] + w1*cs - w0*qc - w1*rs);             // aS_T
        }
        stCur[idx] = cur;
    }
    __syncthreads();

    const int j = sx * 256 + tid;                  // float4 column
    const float wq0 = 1.0f - stCur[2*tid];
    const float wq1 = 1.0f - stCur[2*tid + 1];
    const float bp0 = (T == 0) ? 0.0f : 1.0f - stPrev[2*tid];
    const float bp1 = (T == 0) ? 0.0f : 1.0f - stPrev[2*tid + 1];

    float c0 = 0.0f, c1 = 0.0f;

#pragma unroll
    for (int i = 0; i < RPB; i++) {               // full unroll: d[] stays in regs
        const float a_c = stCur[512 + i];
        float s0, s1;
        if (T == 0) {
            const float4 f = F[(size_t)(row0 + i) * (NN/2) + j];
            d0[i] = f.y - f.x;
            d1[i] = f.w - f.z;
            s0 = fsig(d0[i]);
            s1 = fsig(d1[i]);
        } else {
            const float m1 = w1 * stPrev[512 + i];
            s0 = fsig(d0[i] - m1 * bp0);
            s1 = fsig(d1[i] - m1 * bp1);
        }
        c0 += s0 * a_c;
        c1 += s1 * a_c;
        part[i * PSTR + tid] = s0 * wq0 + s1 * wq1;   // per-row partial
        if (T == 4) {                              // L3-resident F re-read
            const float4 f = F[(size_t)(row0 + i) * (NN/2) + j];
            const float mw = w1 * a_c;
            float4 o;
            o.x = f.x + mw * wq0; o.y = f.y;
            o.z = f.z + mw * wq1; o.w = f.w;
            outF[(size_t)(row0 + i) * (NN/2) + j] = o;
        }
    }

    // c: relaxed fabric atomics into the single per-pass accumulator
    gatomic_add(cout + base + 2*j,     c0);
    gatomic_add(cout + base + 2*j + 1, c1);

    __syncthreads();
    // r: two-stage block reduce, then one relaxed atomic per row (4 writers)
    {
        const int row = tid >> 4, seg = tid & 15;
        float s = 0.0f;
#pragma unroll
        for (int u = 0; u < 16; u++) s += part[row * PSTR + seg * 16 + u];
#pragma unroll
        for (int off = 8; off > 0; off >>= 1) s += __shfl_down(s, off, 16);
        if (seg == 0) gatomic_add(rout + row0 + row, s);
    }
}

// Fused persistent kernel: 5 passes + in-kernel epilogue (no kfin dispatch).
// Coop launch (r2-r4-proven co-residency); fallback is a regular launch of
// this same kernel (r6-proven to complete; SPIN_LIMIT guards).
__global__ __launch_bounds__(256, 4) void kfused(
    const float4* __restrict__ F,
    const float2* __restrict__ S2, const float2* __restrict__ C2,
    const float* __restrict__ w,
    float* __restrict__ ws,
    float2* __restrict__ outS, float2* __restrict__ outC,
    float4* __restrict__ outF)
{
    __shared__ float st[3][512 + RPB]; // rotating aS state
    __shared__ float sdif[512 + RPB];  // S1-S0 (constant across passes)
    __shared__ float cdif[512 + RPB];  // C0-C1 (constant across passes)
    __shared__ float part[16 * PSTR];

    const int tid  = threadIdx.x;
    const int sx   = blockIdx.x;          // 0..3   column split
    const int by   = blockIdx.y;          // 0..255 row group
    const int row0 = by * RPB;
    const int b    = by >> 7;             // batch
    const int bloc = by & 127;            // row group within batch
    const int base = b * NN;
    const int bid  = by * CSPLIT + sx;    // linear block id
    const float w0 = w[0], w1 = w[1];

    float d0[RPB], d1[RPB];               // register-resident F1-F0 (32 VGPR)

    // ws layout (floats): r[5][ROWS] | c[5][ROWS] | bar[NBAR][BARSTRIDE ints]
    float* rb = ws;                      // 5 * ROWS
    float* cb = ws + 5 * ROWS;           // 5 * ROWS
    int*   bar = (int*)(ws + 10 * ROWS);
#define RB(t) (rb + (t) * ROWS)
#define CB(t) (cb + (t) * ROWS)

    do_pass<0>(st[0], st[2], st[1], sdif, cdif, part, d0, d1, F, S2, C2,
               nullptr, nullptr, RB(0), CB(0), nullptr,
               tid, sx, by, bloc, row0, base, w0, w1);
    gridbar(bar + 0*BARSTRIDE, bid);
    do_pass<1>(st[1], st[0], st[2], sdif, cdif, part, d0, d1, F, S2, C2,
               RB(0), CB(0), RB(1), CB(1), nullptr,
               tid, sx, by, bloc, row0, base, w0, w1);
    gridbar(bar + 1*BARSTRIDE, bid);
    do_pass<2>(st[2], st[1], st[0], sdif, cdif, part, d0, d1, F, S2, C2,
               RB(1), CB(1), RB(2), CB(2), nullptr,
               tid, sx, by, bloc, row0, base, w0, w1);
    gridbar(bar + 2*BARSTRIDE, bid);
    do_pass<3>(st[0], st[2], st[1], sdif, cdif, part, d0, d1, F, S2, C2,
               RB(2), CB(2), RB(3), CB(3), nullptr,
               tid, sx, by, bloc, row0, base, w0, w1);
    gridbar(bar + 3*BARSTRIDE, bid);
    do_pass<4>(st[1], st[0], st[2], sdif, cdif, part, d0, d1, F, S2, C2,
               RB(3), CB(3), RB(4), CB(4), outF,
               tid, sx, by, bloc, row0, base, w0, w1);
    gridbar(bar + 4*BARSTRIDE, bid);

    // ---- in-kernel epilogue: 4 rows per block, aS_3/aS_4 from LDS ----
    // rows [4*bid, 4*bid+4) == row0 + 4*sx + [0,4)  (inside this block's 16)
    if (tid < 4) {
        const int lr = 4 * sx + tid;          // row index within block
        const int g  = row0 + lr;             // global row
        const float a4 = st[1][512 + lr];     // aS_4 (pass-4 stCur)
        const float a3 = st[0][512 + lr];     // aS_3 (pass-4 stPrev)
        const float rs = gload(RB(4) + g);
        const float cs = gload(CB(4) + g);
        const float2 sv = S2[g], cv = C2[g];
        const float qc4 = fsig((cv.x - cv.y) - w0 * a3);
        float2 os, oc;
        os.x = sv.x + w0 * qc4 + w1 * rs;
        os.y = sv.y + w1 * cs;
        oc.x = cv.x;
        oc.y = cv.y + w0 * a4;
        outS[g] = os;
        outC[g] = oc;
    }
}

extern "C" void kernel_launch(void* const* d_in, const int* in_sizes, int n_in,
                              void* d_out, int out_size, void* d_ws, size_t ws_size,
                              hipStream_t stream)
{
    const float2* S2 = (const float2*)d_in[0];
    const float2* C2 = (const float2*)d_in[1];
    const float4* F4 = (const float4*)d_in[2];
    const float*  w  = (const float*)d_in[3];
    float* out = (float*)d_out;
    float* ws  = (float*)d_ws;

    float2* outS = (float2*)out;
    float2* outC = (float2*)(out + 2 * ROWS);
    float4* outF = (float4*)(out + 4 * ROWS);

    // one memset: r[5]+c[5] accumulators + all barrier counters (contiguous);
    // in-graph so everything resets on every replay
    hipMemsetAsync(ws, 0,
                   10 * (size_t)ROWS * sizeof(float)
                   + (size_t)NBAR * BARSTRIDE * sizeof(int), stream);

    dim3 gb(CSPLIT, NBY), bb(256, 1, 1);
    void* args[] = { (void*)&F4, (void*)&S2, (void*)&C2, (void*)&w,
                     (void*)&ws, (void*)&outS, (void*)&outC, (void*)&outF };
    hipError_t ce = hipLaunchCooperativeKernel((const void*)kfused, gb, bb,
                                               args, 0, stream);
    if (ce != hipSuccess) {
        // coop rejected: clear sticky error, regular launch of the same kernel
        // (r6-proven pattern; SPIN_LIMIT prevents a dead container)
        (void)hipGetLastError();
        kfused<<<gb, bb, 0, stream>>>(F4, S2, C2, w, ws, outS, outC, outF);
    }
}

// Round 9
// 196.017 us; speedup vs baseline: 1.2228x; 1.0612x over previous
//
#include <hip/hip_runtime.h>

#define NN   2048
#define ROWS 4096          // B*N
#define RPB  16            // rows per block (d[16] register-proven)
#define CSPLIT 4           // column splits; block covers 256 float4 cols
#define NBY  (ROWS/RPB)    // 256
#define NCSL 4             // c-accumulator slices: 32 writers/addr, 4 prologue loads
#define PSTR 257           // LDS partial stride
#define NBLK (CSPLIT*NBY)  // 1024 blocks = 4/CU

#define SUBW 32            // arrivals per sub-counter
#define NSUB (NBLK/SUBW)   // 32 sub-counters
#define CPAD 16            // ints per counter (64B padding)
#define BARSTRIDE ((NSUB+1)*CPAD)   // ints per barrier instance
#define NBAR 5             // 4 inter-pass + 1 pre-epilogue
#define SPIN_LIMIT (1<<21) // ~100ms escape: wrong-answer beats dead-container

typedef float vfloat4 __attribute__((ext_vector_type(4)));  // native vec for NT store

__device__ __forceinline__ float fsig(float x) {
    float e = __expf(-x);
    return __builtin_amdgcn_rcpf(1.0f + e);
}

// Agent-scope relaxed atomics: cross-XCD-coherent data path (execute at the
// coherence point).  No fences, no L2 writeback/invalidate (round-3 lesson).
__device__ __forceinline__ float gload(const float* p) {
    return __hip_atomic_load(p, __ATOMIC_RELAXED, __HIP_MEMORY_SCOPE_AGENT);
}
__device__ __forceinline__ void gatomic_add(float* p, float v) {
    __hip_atomic_fetch_add(p, v, __ATOMIC_RELAXED, __HIP_MEMORY_SCOPE_AGENT);
}

// Fully-relaxed two-level grid barrier (r4/r7-proven).  __syncthreads drains
// vmcnt(0) so all sc1 stores/atomics reached the coherence point before the
// arrive; readers use sc1 loads -> relaxed suffices end-to-end.
__device__ __forceinline__ void gridbar(int* cnt, int bid) {
    __syncthreads();                      // s_waitcnt vmcnt(0) + s_barrier
    if (threadIdx.x == 0) {
        asm volatile("" ::: "memory");
        int* sub  = cnt + (bid & (NSUB - 1)) * CPAD;
        int* root = cnt + NSUB * CPAD;
        int old = __hip_atomic_fetch_add(sub, 1, __ATOMIC_RELAXED,
                                         __HIP_MEMORY_SCOPE_AGENT);
        if (old == SUBW - 1)
            __hip_atomic_fetch_add(root, 1, __ATOMIC_RELAXED,
                                   __HIP_MEMORY_SCOPE_AGENT);
        int tries = 0;
        while (__hip_atomic_load(root, __ATOMIC_RELAXED,
                                 __HIP_MEMORY_SCOPE_AGENT) < NSUB) {
            __builtin_amdgcn_s_sleep(1);
            if (++tries > SPIN_LIMIT) break;
        }
        asm volatile("" ::: "memory");
    }
    __syncthreads();
}

// ---------------------------------------------------------------------------
// One pass over 16 rows x 256 f4-cols.  r: single accumulator (4 writers/row).
// c: NCSL=4 slices (32 writers/addr — r4-class contention, 4 prologue loads).
// d0/d1[16]: register-resident F1-F0 (filled at T==0; no spill at VGPR~64).
// T==4 re-reads F (L3-resident) and NT-stores outF.
// ---------------------------------------------------------------------------
template<int T>
__device__ __forceinline__ void do_pass(
    float* __restrict__ stCur, const float* __restrict__ stPrev,
    const float* __restrict__ stPP,
    float* __restrict__ sdif, float* __restrict__ cdif,
    float* __restrict__ part,
    float (&d0)[RPB], float (&d1)[RPB],
    const float4* __restrict__ F,
    const float2* __restrict__ S2, const float2* __restrict__ C2,
    const float* __restrict__ rprev, const float* __restrict__ cprev,
    float* __restrict__ rout, float* __restrict__ cout,
    float4* __restrict__ outF,
    int tid, int sx, int by, int bloc, int row0, int base,
    float w0, float w1)
{
    // ---- prologue: state for the 528 indices this block touches ----
    for (int idx = tid; idx < 512 + RPB; idx += 256) {
        int il = (idx < 512) ? (sx * 512 + idx) : (bloc * RPB + idx - 512);
        int g  = base + il;
        float cur;
        if (T == 0) {
            float2 sv = S2[g], cv = C2[g];
            float sd = sv.y - sv.x;
            sdif[idx] = sd;
            cdif[idx] = cv.x - cv.y;
            cur = fsig(sd);                       // aS_0
        } else {
            float rs = gload(rprev + g);          // summed r_{T-1}
            float cs = 0.0f;
#pragma unroll
            for (int s = 0; s < NCSL; s++) cs += gload(cprev + s*ROWS + g);
            float qc = (T == 1) ? fsig(cdif[idx])                      // qC0_0
                                : fsig(cdif[idx] - w0 * stPP[idx]);    // qC0_{T-1}
            cur = fsig(sdif[idx] + w1*cs - w0*qc - w1*rs);             // aS_T
        }
        stCur[idx] = cur;
    }
    __syncthreads();

    const int j = sx * 256 + tid;                  // float4 column
    const float wq0 = 1.0f - stCur[2*tid];
    const float wq1 = 1.0f - stCur[2*tid + 1];
    const float bp0 = (T == 0) ? 0.0f : 1.0f - stPrev[2*tid];
    const float bp1 = (T == 0) ? 0.0f : 1.0f - stPrev[2*tid + 1];

    float c0 = 0.0f, c1 = 0.0f;

#pragma unroll
    for (int i = 0; i < RPB; i++) {               // full unroll: d[] stays in regs
        const float a_c = stCur[512 + i];
        float s0, s1;
        if (T == 0) {
            const float4 f = F[(size_t)(row0 + i) * (NN/2) + j];
            d0[i] = f.y - f.x;
            d1[i] = f.w - f.z;
            s0 = fsig(d0[i]);
            s1 = fsig(d1[i]);
        } else {
            const float m1 = w1 * stPrev[512 + i];
            s0 = fsig(d0[i] - m1 * bp0);
            s1 = fsig(d1[i] - m1 * bp1);
        }
        c0 += s0 * a_c;
        c1 += s1 * a_c;
        part[i * PSTR + tid] = s0 * wq0 + s1 * wq1;   // per-row partial
        if (T == 4) {                              // L3-resident F re-read
            const float4 f = F[(size_t)(row0 + i) * (NN/2) + j];
            const float mw = w1 * a_c;
            vfloat4 o;
            o.x = f.x + mw * wq0; o.y = f.y;
            o.z = f.z + mw * wq1; o.w = f.w;
            // outF is never re-read: NT store avoids evicting L3-resident F.
            // (native ext_vector type: __builtin_nontemporal_store rejects
            // HIP_vector_type float4 — round-8 compile error)
            __builtin_nontemporal_store(
                o, (vfloat4*)&outF[(size_t)(row0 + i) * (NN/2) + j]);
        }
    }

    // c: sliced relaxed fabric atomics (32 writers/addr)
    gatomic_add(cout + (by & (NCSL-1))*ROWS + base + 2*j,     c0);
    gatomic_add(cout + (by & (NCSL-1))*ROWS + base + 2*j + 1, c1);

    __syncthreads();
    // r: two-stage block reduce.  Read order rotated per-lane so the 16 segs
    // hit 16 distinct banks (was: seg*16 on 2 banks -> 8-way conflict, the
    // 4.59M SQ_LDS_BANK_CONFLICT seen every round).  Sum set is unchanged.
    {
        const int row = tid >> 4, seg = tid & 15;
        float s = 0.0f;
#pragma unroll
        for (int u = 0; u < 16; u++)
            s += part[row * PSTR + seg * 16 + ((seg + u) & 15)];
#pragma unroll
        for (int off = 8; off > 0; off >>= 1) s += __shfl_down(s, off, 16);
        if (seg == 0) gatomic_add(rout + row0 + row, s);
    }
}

// Fused persistent kernel: 5 passes + in-kernel epilogue.
// Coop launch (co-residency guarantee) with regular-launch fallback
// (r6-proven to complete; SPIN_LIMIT guards against a dead container).
__global__ __launch_bounds__(256, 4) void kfused(
    const float4* __restrict__ F,
    const float2* __restrict__ S2, const float2* __restrict__ C2,
    const float* __restrict__ w,
    float* __restrict__ ws,
    float2* __restrict__ outS, float2* __restrict__ outC,
    float4* __restrict__ outF)
{
    __shared__ float st[3][512 + RPB]; // rotating aS state
    __shared__ float sdif[512 + RPB];  // S1-S0 (constant across passes)
    __shared__ float cdif[512 + RPB];  // C0-C1 (constant across passes)
    __shared__ float part[16 * PSTR];

    const int tid  = threadIdx.x;
    const int sx   = blockIdx.x;          // 0..3   column split
    const int by   = blockIdx.y;          // 0..255 row group
    const int row0 = by * RPB;
    const int b    = by >> 7;             // batch
    const int bloc = by & 127;            // row group within batch
    const int base = b * NN;
    const int bid  = by * CSPLIT + sx;    // linear block id
    const float w0 = w[0], w1 = w[1];

    float d0[RPB], d1[RPB];               // register-resident F1-F0 (32 VGPR)

    // ws layout (floats): r[5][ROWS] | c[5][NCSL][ROWS] | bar
    float* rb = ws;                           // 5 * ROWS
    float* cb = ws + 5 * ROWS;                // 5 * NCSL * ROWS
    int*   bar = (int*)(ws + (5 + 5*NCSL) * ROWS);
#define RB(t) (rb + (t) * ROWS)
#define CB(t) (cb + (t) * (NCSL * ROWS))

    do_pass<0>(st[0], st[2], st[1], sdif, cdif, part, d0, d1, F, S2, C2,
               nullptr, nullptr, RB(0), CB(0), nullptr,
               tid, sx, by, bloc, row0, base, w0, w1);
    gridbar(bar + 0*BARSTRIDE, bid);
    do_pass<1>(st[1], st[0], st[2], sdif, cdif, part, d0, d1, F, S2, C2,
               RB(0), CB(0), RB(1), CB(1), nullptr,
               tid, sx, by, bloc, row0, base, w0, w1);
    gridbar(bar + 1*BARSTRIDE, bid);
    do_pass<2>(st[2], st[1], st[0], sdif, cdif, part, d0, d1, F, S2, C2,
               RB(1), CB(1), RB(2), CB(2), nullptr,
               tid, sx, by, bloc, row0, base, w0, w1);
    gridbar(bar + 2*BARSTRIDE, bid);
    do_pass<3>(st[0], st[2], st[1], sdif, cdif, part, d0, d1, F, S2, C2,
               RB(2), CB(2), RB(3), CB(3), nullptr,
               tid, sx, by, bloc, row0, base, w0, w1);
    gridbar(bar + 3*BARSTRIDE, bid);
    do_pass<4>(st[1], st[0], st[2], sdif, cdif, part, d0, d1, F, S2, C2,
               RB(3), CB(3), RB(4), CB(4), outF,
               tid, sx, by, bloc, row0, base, w0, w1);
    gridbar(bar + 4*BARSTRIDE, bid);

    // ---- in-kernel epilogue: 4 rows per block, aS_3/aS_4 from LDS ----
    // rows [4*bid, 4*bid+4) == row0 + 4*sx + [0,4)  (inside this block's 16)
    if (tid < 4) {
        const int lr = 4 * sx + tid;          // row index within block
        const int g  = row0 + lr;             // global row
        const float a4 = st[1][512 + lr];     // aS_4 (pass-4 stCur)
        const float a3 = st[0][512 + lr];     // aS_3 (pass-4 stPrev)
        const float rs = gload(RB(4) + g);
        float cs = 0.0f;
#pragma unroll
        for (int s = 0; s < NCSL; s++) cs += gload(CB(4) + s*ROWS + g);
        const float2 sv = S2[g], cv = C2[g];
        const float qc4 = fsig((cv.x - cv.y) - w0 * a3);
        float2 os, oc;
        os.x = sv.x + w0 * qc4 + w1 * rs;
        os.y = sv.y + w1 * cs;
        oc.x = cv.x;
        oc.y = cv.y + w0 * a4;
        outS[g] = os;
        outC[g] = oc;
    }
}

extern "C" void kernel_launch(void* const* d_in, const int* in_sizes, int n_in,
                              void* d_out, int out_size, void* d_ws, size_t ws_size,
                              hipStream_t stream)
{
    const float2* S2 = (const float2*)d_in[0];
    const float2* C2 = (const float2*)d_in[1];
    const float4* F4 = (const float4*)d_in[2];
    const float*  w  = (const float*)d_in[3];
    float* out = (float*)d_out;
    float* ws  = (float*)d_ws;

    float2* outS = (float2*)out;
    float2* outC = (float2*)(out + 2 * ROWS);
    float4* outF = (float4*)(out + 4 * ROWS);

    // one memset: r[5]+c[5][NCSL] accumulators + all barrier counters
    // (contiguous); in-graph so everything resets on every replay
    (void)hipMemsetAsync(ws, 0,
                         (5 + 5*NCSL) * (size_t)ROWS * sizeof(float)
                         + (size_t)NBAR * BARSTRIDE * sizeof(int), stream);

    dim3 gb(CSPLIT, NBY), bb(256, 1, 1);
    void* args[] = { (void*)&F4, (void*)&S2, (void*)&C2, (void*)&w,
                     (void*)&ws, (void*)&outS, (void*)&outC, (void*)&outF };
    hipError_t ce = hipLaunchCooperativeKernel((const void*)kfused, gb, bb,
                                               args, 0, stream);
    if (ce != hipSuccess) {
        // coop rejected: clear sticky error, regular launch of the same kernel
        (void)hipGetLastError();
        kfused<<<gb, bb, 0, stream>>>(F4, S2, C2, w, ws, outS, outC, outF);
    }
}